// Round 1
// baseline (106.964 us; speedup 1.0000x reference)
//
#include <hip/hip_runtime.h>
#include <math.h>

// Problem constants (B=4096, D=128, H=512)
#define B_ 4096
#define D_ 128
#define H_ 512

#define BR 8          // rows per block
#define YT_STRIDE 12  // floats per yT row (16B aligned: 12*4=48)
#define HT_STRIDE 12  // floats per hT row

// s[k] = sum_i W1[i][k] * W2[k][i]
__global__ __launch_bounds__(256) void s_kernel(const float* __restrict__ W1,
                                                const float* __restrict__ W2,
                                                float* __restrict__ s) {
    int k = blockIdx.x * 256 + threadIdx.x;  // 0..511
    float a = 0.f;
#pragma unroll 8
    for (int i = 0; i < D_; ++i) {
        a = fmaf(W1[i * H_ + k], W2[k * D_ + i], a);
    }
    s[k] = a;
}

__global__ __launch_bounds__(256) void ode_fused(const float* __restrict__ t_,
                                                 const float* __restrict__ y,
                                                 const float* __restrict__ W1,
                                                 const float* __restrict__ b1,
                                                 const float* __restrict__ v1,
                                                 const float* __restrict__ W2,
                                                 const float* __restrict__ b2,
                                                 const float* __restrict__ s,
                                                 float* __restrict__ out) {
    __shared__ __align__(16) float yT[D_ * YT_STRIDE];   // yT[i*12 + r] = y[r][i]
    __shared__ __align__(16) float hT[H_ * HT_STRIDE];   // hT[k*12 + r] = h[r][k]
    __shared__ float wdiv[4][BR];

    const int tid = threadIdx.x;
    const int row0 = blockIdx.x * BR;

    // ---- stage y tile (transposed) ----
    for (int e = tid; e < BR * D_; e += 256) {
        int r = e >> 7;          // e / 128
        int i = e & (D_ - 1);    // e % 128
        yT[i * YT_STRIDE + r] = y[(size_t)(row0 + r) * D_ + i];
    }
    __syncthreads();

    // ---- phase 1: h = tanh(y@W1 + t*v1 + b1), thread owns columns k0,k1 ----
    const int k0 = tid;
    const int k1 = tid + 256;
    const float t = t_[0];
    const float pre0 = fmaf(t, v1[k0], b1[k0]);
    const float pre1 = fmaf(t, v1[k1], b1[k1]);

    float acc0[BR], acc1[BR];
#pragma unroll
    for (int r = 0; r < BR; ++r) { acc0[r] = pre0; acc1[r] = pre1; }

#pragma unroll 8
    for (int i = 0; i < D_; ++i) {
        float w0 = W1[i * H_ + k0];
        float w1 = W1[i * H_ + k1];
        const float4 ya = *(const float4*)&yT[i * YT_STRIDE];
        const float4 yb = *(const float4*)&yT[i * YT_STRIDE + 4];
        acc0[0] = fmaf(ya.x, w0, acc0[0]);
        acc0[1] = fmaf(ya.y, w0, acc0[1]);
        acc0[2] = fmaf(ya.z, w0, acc0[2]);
        acc0[3] = fmaf(ya.w, w0, acc0[3]);
        acc0[4] = fmaf(yb.x, w0, acc0[4]);
        acc0[5] = fmaf(yb.y, w0, acc0[5]);
        acc0[6] = fmaf(yb.z, w0, acc0[6]);
        acc0[7] = fmaf(yb.w, w0, acc0[7]);
        acc1[0] = fmaf(ya.x, w1, acc1[0]);
        acc1[1] = fmaf(ya.y, w1, acc1[1]);
        acc1[2] = fmaf(ya.z, w1, acc1[2]);
        acc1[3] = fmaf(ya.w, w1, acc1[3]);
        acc1[4] = fmaf(yb.x, w1, acc1[4]);
        acc1[5] = fmaf(yb.y, w1, acc1[5]);
        acc1[6] = fmaf(yb.z, w1, acc1[6]);
        acc1[7] = fmaf(yb.w, w1, acc1[7]);
    }

    const float sk0 = s[k0];
    const float sk1 = s[k1];
    float c[BR];
#pragma unroll
    for (int r = 0; r < BR; ++r) {
        float h0 = tanhf(acc0[r]);
        float h1 = tanhf(acc1[r]);
        hT[k0 * HT_STRIDE + r] = h0;
        hT[k1 * HT_STRIDE + r] = h1;
        c[r] = (1.f - h0 * h0) * sk0 + (1.f - h1 * h1) * sk1;
    }

    // wave-level reduction of divergence contributions (64 lanes)
#pragma unroll
    for (int r = 0; r < BR; ++r) {
        float v = c[r];
        v += __shfl_down(v, 32, 64);
        v += __shfl_down(v, 16, 64);
        v += __shfl_down(v, 8, 64);
        v += __shfl_down(v, 4, 64);
        v += __shfl_down(v, 2, 64);
        v += __shfl_down(v, 1, 64);
        c[r] = v;
    }
    if ((tid & 63) == 0) {
        int w = tid >> 6;
#pragma unroll
        for (int r = 0; r < BR; ++r) wdiv[w][r] = c[r];
    }
    __syncthreads();

    // ---- divergence output ----
    if (tid < BR) {
        float dv = wdiv[0][tid] + wdiv[1][tid] + wdiv[2][tid] + wdiv[3][tid];
        out[(size_t)B_ * D_ + row0 + tid] = -dv;
    }

    // ---- phase 2: dy = h @ W2 + b2 ----
    const int d = tid & (D_ - 1);
    const int half = tid >> 7;
    const int rb = half * 4;

    float acc2[4];
    const float bb = b2[d];
#pragma unroll
    for (int j = 0; j < 4; ++j) acc2[j] = bb;

#pragma unroll 8
    for (int k = 0; k < H_; ++k) {
        float w = W2[k * D_ + d];
        const float4 hv = *(const float4*)&hT[k * HT_STRIDE + rb];
        acc2[0] = fmaf(hv.x, w, acc2[0]);
        acc2[1] = fmaf(hv.y, w, acc2[1]);
        acc2[2] = fmaf(hv.z, w, acc2[2]);
        acc2[3] = fmaf(hv.w, w, acc2[3]);
    }
#pragma unroll
    for (int j = 0; j < 4; ++j) {
        out[(size_t)(row0 + rb + j) * D_ + d] = acc2[j];
    }
}

extern "C" void kernel_launch(void* const* d_in, const int* in_sizes, int n_in,
                              void* d_out, int out_size, void* d_ws, size_t ws_size,
                              hipStream_t stream) {
    const float* t  = (const float*)d_in[0];
    const float* y  = (const float*)d_in[1];
    // d_in[2] = logp (unused by outputs)
    const float* W1 = (const float*)d_in[3];
    const float* b1 = (const float*)d_in[4];
    const float* v1 = (const float*)d_in[5];
    const float* W2 = (const float*)d_in[6];
    const float* b2 = (const float*)d_in[7];
    float* out = (float*)d_out;
    float* s = (float*)d_ws;  // 512 floats

    s_kernel<<<2, 256, 0, stream>>>(W1, W2, s);
    ode_fused<<<B_ / BR, 256, 0, stream>>>(t, y, W1, b1, v1, W2, b2, s, out);
}

// Round 2
// 83.384 us; speedup vs baseline: 1.2828x; 1.2828x over previous
//
#include <hip/hip_runtime.h>

// B=4096, D=128, H=512
#define B_ 4096
#define D_ 128
#define H_ 512

typedef short v8s __attribute__((ext_vector_type(8)));   // 8 bf16 (4 VGPRs)
typedef float v4f __attribute__((ext_vector_type(4)));   // MFMA accumulator

__device__ __forceinline__ unsigned short f2bf(float f) {
    unsigned int u = __float_as_uint(f);
    u += 0x7fffu + ((u >> 16) & 1u);   // RNE
    return (unsigned short)(u >> 16);
}

// ---------------------------------------------------------------------------
// prep: yb = bf16(y); W1T[H][D] = bf16(W1^T); W2T[D][H] = bf16(W2^T);
//       s[k] = sum_i W1[i][k] * W2[k][i]
// grid roles: blk 0..63 y-convert, 64..127 W1T, 128..191 W2T, 192..199 s
// ---------------------------------------------------------------------------
__global__ __launch_bounds__(256) void prep_kernel(
    const float* __restrict__ y, const float* __restrict__ W1,
    const float* __restrict__ W2,
    unsigned short* __restrict__ yb, unsigned short* __restrict__ W1T,
    unsigned short* __restrict__ W2T, float* __restrict__ s)
{
    __shared__ __align__(16) float smem[8448];
    const int tid = threadIdx.x;
    const int blk = blockIdx.x;

    if (blk < 64) {
        int idx = blk * 256 + tid;               // float4 id
#pragma unroll
        for (int i = 0; i < 8; ++i) {
            int e = idx + i * 16384;             // 131072 float4 total
            float4 v = ((const float4*)y)[e];
            ushort4 o;
            o.x = f2bf(v.x); o.y = f2bf(v.y); o.z = f2bf(v.z); o.w = f2bf(v.w);
            ((ushort4*)yb)[e] = o;
        }
    } else if (blk < 192) {
        float (*tile)[33] = (float(*)[33])smem;
        const float* src; unsigned short* dst;
        int srcC, dstC, r0, c0;
        if (blk < 128) {                          // W1: 128x512 -> W1T 512x128
            int tt = blk - 64;                    // 4 x 16 tiles
            src = W1; dst = W1T; srcC = 512; dstC = 128;
            r0 = (tt >> 4) * 32; c0 = (tt & 15) * 32;
        } else {                                  // W2: 512x128 -> W2T 128x512
            int tt = blk - 128;                   // 16 x 4 tiles
            src = W2; dst = W2T; srcC = 128; dstC = 512;
            r0 = (tt >> 2) * 32; c0 = (tt & 3) * 32;
        }
        int c = tid & 31, r = tid >> 5;
#pragma unroll
        for (int i = 0; i < 4; ++i)
            tile[r + i * 8][c] = src[(r0 + r + i * 8) * srcC + c0 + c];
        __syncthreads();
        int rw = tid & 31, cw = tid >> 5;
#pragma unroll
        for (int i = 0; i < 4; ++i)
            dst[(c0 + cw + i * 8) * dstC + r0 + rw] = f2bf(tile[rw][cw + i * 8]);
    } else {
        int kbase = (blk - 192) * 64;
        for (int e = tid; e < 8192; e += 256) {
            int kk = e >> 7, i = e & 127;
            smem[kk * 132 + i] = W2[(kbase + kk) * 128 + i];
        }
        __syncthreads();
        int kk = tid >> 2, sub = tid & 3;
        int k = kbase + kk;
        float a = 0.f;
#pragma unroll 8
        for (int j = 0; j < 32; ++j) {
            int i = sub * 32 + j;
            a = fmaf(W1[i * H_ + k], smem[kk * 132 + i], a);
        }
        a += __shfl_xor(a, 1, 64);
        a += __shfl_xor(a, 2, 64);
        if (sub == 0) s[k] = a;
    }
}

// ---------------------------------------------------------------------------
// main kernel: 16 rows/block, 4 waves.
// MFMA 16x16x32_bf16 layouts (HW-verified): A[m=lane&15][k=quad*8+j],
// B[k=quad*8+j][n=lane&15], C/D: col=lane&15, row=quad*4+reg.
// ---------------------------------------------------------------------------
__global__ __launch_bounds__(256) void ode_mfma(
    const float* __restrict__ t_, const unsigned short* __restrict__ yb,
    const unsigned short* __restrict__ W1T, const unsigned short* __restrict__ W2T,
    const float* __restrict__ sg, const float* __restrict__ b1g,
    const float* __restrict__ v1g, const float* __restrict__ b2g,
    float* __restrict__ out)
{
    __shared__ __align__(16) unsigned short hsm[16 * 520];  // +8 pad: 2-way only
    __shared__ float divp[4][16];

    const int tid  = threadIdx.x;
    const int lane = tid & 63;
    const int wv   = tid >> 6;       // 0..3
    const int m    = lane & 15;
    const int quad = lane >> 4;      // 0..3
    const int row0 = blockIdx.x * 16;
    const float t  = t_[0];

    // ---- GEMM1 A-fragments (reused across this wave's 8 H-tiles) ----
    v8s af[4];
    const v8s* yrow = (const v8s*)&yb[(row0 + m) * D_ + quad * 8];
#pragma unroll
    for (int kki = 0; kki < 4; ++kki) af[kki] = yrow[kki * 4];

    float dacc[4] = {0.f, 0.f, 0.f, 0.f};

#pragma unroll 2
    for (int i = 0; i < 8; ++i) {
        const int n = (wv * 8 + i) * 16 + m;
        const v8s* wp = (const v8s*)&W1T[n * D_ + quad * 8];
        v8s bf0 = wp[0], bf1 = wp[4], bf2 = wp[8], bf3 = wp[12];
        v4f acc = {0.f, 0.f, 0.f, 0.f};
        acc = __builtin_amdgcn_mfma_f32_16x16x32_bf16(af[0], bf0, acc, 0, 0, 0);
        acc = __builtin_amdgcn_mfma_f32_16x16x32_bf16(af[1], bf1, acc, 0, 0, 0);
        acc = __builtin_amdgcn_mfma_f32_16x16x32_bf16(af[2], bf2, acc, 0, 0, 0);
        acc = __builtin_amdgcn_mfma_f32_16x16x32_bf16(af[3], bf3, acc, 0, 0, 0);

        const float pre = fmaf(t, v1g[n], b1g[n]);
        const float sk  = sg[n];
#pragma unroll
        for (int reg = 0; reg < 4; ++reg) {
            float x  = acc[reg] + pre;
            float e  = __expf(2.f * x);                       // v_exp path
            float th = 1.f - 2.f * __builtin_amdgcn_rcpf(e + 1.f);
            hsm[(quad * 4 + reg) * 520 + n] = f2bf(th);
            dacc[reg] = fmaf(1.f - th * th, sk, dacc[reg]);
        }
    }

#pragma unroll
    for (int reg = 0; reg < 4; ++reg) {
        float v = dacc[reg];
        v += __shfl_xor(v, 1, 64);
        v += __shfl_xor(v, 2, 64);
        v += __shfl_xor(v, 4, 64);
        v += __shfl_xor(v, 8, 64);
        dacc[reg] = v;
    }
    if (m == 0) {
#pragma unroll
        for (int reg = 0; reg < 4; ++reg) divp[wv][quad * 4 + reg] = dacc[reg];
    }
    __syncthreads();

    if (tid < 16) {
        float dv = divp[0][tid] + divp[1][tid] + divp[2][tid] + divp[3][tid];
        out[B_ * D_ + row0 + tid] = -dv;
    }

    // ---- GEMM2: dy = h @ W2 + b2 ; wave owns d-tiles d0 and d0+16 ----
    const int d0 = wv * 32;
    const int dA = d0 + m, dB = d0 + 16 + m;
    v4f acc0 = {0.f, 0.f, 0.f, 0.f}, acc1 = {0.f, 0.f, 0.f, 0.f};
    const v8s* hrow = (const v8s*)&hsm[m * 520 + quad * 8];   // step kk: +4 v8s
    const v8s* w2a  = (const v8s*)&W2T[dA * H_ + quad * 8];
    const v8s* w2b  = (const v8s*)&W2T[dB * H_ + quad * 8];
#pragma unroll 4
    for (int kki = 0; kki < 16; ++kki) {
        v8s a  = hrow[kki * 4];
        v8s b0 = w2a[kki * 4];
        v8s b1 = w2b[kki * 4];
        acc0 = __builtin_amdgcn_mfma_f32_16x16x32_bf16(a, b0, acc0, 0, 0, 0);
        acc1 = __builtin_amdgcn_mfma_f32_16x16x32_bf16(a, b1, acc1, 0, 0, 0);
    }
    const float be0 = b2g[dA], be1 = b2g[dB];
#pragma unroll
    for (int reg = 0; reg < 4; ++reg) {
        const int r = row0 + quad * 4 + reg;
        out[r * D_ + dA] = acc0[reg] + be0;
        out[r * D_ + dB] = acc1[reg] + be1;
    }
}

extern "C" void kernel_launch(void* const* d_in, const int* in_sizes, int n_in,
                              void* d_out, int out_size, void* d_ws, size_t ws_size,
                              hipStream_t stream) {
    const float* t  = (const float*)d_in[0];
    const float* y  = (const float*)d_in[1];
    // d_in[2] = logp (unused)
    const float* W1 = (const float*)d_in[3];
    const float* b1 = (const float*)d_in[4];
    const float* v1 = (const float*)d_in[5];
    const float* W2 = (const float*)d_in[6];
    const float* b2 = (const float*)d_in[7];
    float* out = (float*)d_out;

    char* ws = (char*)d_ws;
    unsigned short* yb  = (unsigned short*)(ws);             // 1,048,576 B
    unsigned short* W1T = (unsigned short*)(ws + 1048576);   //   131,072 B
    unsigned short* W2T = (unsigned short*)(ws + 1179648);   //   131,072 B
    float*          s   = (float*)(ws + 1310720);            //     2,048 B

    prep_kernel<<<200, 256, 0, stream>>>(y, W1, W2, yb, W1T, W2T, s);
    ode_mfma<<<B_ / 16, 256, 0, stream>>>(t, yb, W1T, W2T, s, b1, v1, b2, out);
}

// Round 3
// 83.335 us; speedup vs baseline: 1.2835x; 1.0006x over previous
//
#include <hip/hip_runtime.h>

// B=4096, D=128, H=512
#define B_ 4096
#define D_ 128
#define H_ 512

typedef short v8s __attribute__((ext_vector_type(8)));   // 8 bf16 (4 VGPRs)
typedef float v4f __attribute__((ext_vector_type(4)));   // MFMA accumulator

__device__ __forceinline__ unsigned short f2bf(float f) {
    unsigned int u = __float_as_uint(f);
    u += 0x7fffu + ((u >> 16) & 1u);   // RNE
    return (unsigned short)(u >> 16);
}

__device__ __forceinline__ v8s cvt8(float4 a, float4 b) {
    v8s r;
    r[0] = (short)f2bf(a.x); r[1] = (short)f2bf(a.y);
    r[2] = (short)f2bf(a.z); r[3] = (short)f2bf(a.w);
    r[4] = (short)f2bf(b.x); r[5] = (short)f2bf(b.y);
    r[6] = (short)f2bf(b.z); r[7] = (short)f2bf(b.w);
    return r;
}

// ---------------------------------------------------------------------------
// prep: W1T[H][D] = bf16(W1^T); W2T[D][H] = bf16(W2^T);
//       s[k] = sum_i W1[i][k] * W2[k][i]
// grid roles: blk 0..63 W1T, 64..127 W2T, 128..135 s
// ---------------------------------------------------------------------------
__global__ __launch_bounds__(256) void prep_kernel(
    const float* __restrict__ W1, const float* __restrict__ W2,
    unsigned short* __restrict__ W1T, unsigned short* __restrict__ W2T,
    float* __restrict__ s)
{
    __shared__ __align__(16) float smem[8448];
    const int tid = threadIdx.x;
    const int blk = blockIdx.x;

    if (blk < 128) {
        // 32x32 LDS tile transpose + convert
        float (*tile)[33] = (float(*)[33])smem;
        const float* src; unsigned short* dst;
        int srcC, dstC, r0, c0;
        if (blk < 64) {                           // W1: 128x512 -> W1T 512x128
            int tt = blk;                         // 4 x 16 tiles
            src = W1; dst = W1T; srcC = 512; dstC = 128;
            r0 = (tt >> 4) * 32; c0 = (tt & 15) * 32;
        } else {                                  // W2: 512x128 -> W2T 128x512
            int tt = blk - 64;                    // 16 x 4 tiles
            src = W2; dst = W2T; srcC = 128; dstC = 512;
            r0 = (tt >> 2) * 32; c0 = (tt & 3) * 32;
        }
        int c = tid & 31, r = tid >> 5;
#pragma unroll
        for (int i = 0; i < 4; ++i)
            tile[r + i * 8][c] = src[(r0 + r + i * 8) * srcC + c0 + c];
        __syncthreads();
        int rw = tid & 31, cw = tid >> 5;
#pragma unroll
        for (int i = 0; i < 4; ++i)
            dst[(c0 + cw + i * 8) * dstC + r0 + rw] = f2bf(tile[rw][cw + i * 8]);
    } else {
        // s[k]: 8 blocks x 64 k each; W2 rows staged in LDS (pad 132)
        int kbase = (blk - 128) * 64;
        for (int e = tid; e < 8192; e += 256) {
            int kk = e >> 7, i = e & 127;
            smem[kk * 132 + i] = W2[(kbase + kk) * 128 + i];
        }
        __syncthreads();
        int kk = tid >> 2, sub = tid & 3;         // 4 threads per k
        int k = kbase + kk;
        float a = 0.f;
#pragma unroll 8
        for (int j = 0; j < 32; ++j) {
            int i = sub * 32 + j;
            a = fmaf(W1[i * H_ + k], smem[kk * 132 + i], a);
        }
        a += __shfl_xor(a, 1, 64);
        a += __shfl_xor(a, 2, 64);
        if (sub == 0) s[k] = a;
    }
}

// ---------------------------------------------------------------------------
// main kernel: 16 rows/block, 512 threads (8 waves -> 2 waves/SIMD).
// MFMA 16x16x32_bf16 layouts (HW-verified): A[m=lane&15][k=quad*8+j],
// B[k=quad*8+j][n=lane&15], C/D: col=lane&15, row=quad*4+reg.
// GEMM1: wave owns 4 H-tiles. GEMM2: wave owns 1 d-tile, W2 frags
// prefetched before the barrier so L2 latency hides behind the sync.
// ---------------------------------------------------------------------------
__global__ __launch_bounds__(512) void ode_mfma(
    const float* __restrict__ t_, const float* __restrict__ y,
    const unsigned short* __restrict__ W1T, const unsigned short* __restrict__ W2T,
    const float* __restrict__ sg, const float* __restrict__ b1g,
    const float* __restrict__ v1g, const float* __restrict__ b2g,
    float* __restrict__ out)
{
    __shared__ __align__(16) unsigned short hsm[16 * 520];  // +8 pad
    __shared__ float divp[8][16];

    const int tid  = threadIdx.x;
    const int lane = tid & 63;
    const int wv   = tid >> 6;       // 0..7
    const int m    = lane & 15;
    const int quad = lane >> 4;      // 0..3
    const int row0 = blockIdx.x * 16;
    const float t  = t_[0];

    // ---- A-fragments: load y (fp32) directly, convert in registers ----
    v8s af[4];
    {
        const float4* yrow = (const float4*)&y[(row0 + m) * D_];
#pragma unroll
        for (int kki = 0; kki < 4; ++kki) {
            float4 a = yrow[kki * 8 + quad * 2];
            float4 b = yrow[kki * 8 + quad * 2 + 1];
            af[kki] = cvt8(a, b);
        }
    }

    float dacc[4] = {0.f, 0.f, 0.f, 0.f};

    // ---- GEMM1: 4 H-tiles per wave ----
#pragma unroll 2
    for (int i = 0; i < 4; ++i) {
        const int n = (wv * 4 + i) * 16 + m;
        const v8s* wp = (const v8s*)&W1T[n * D_ + quad * 8];
        v8s bf0 = wp[0], bf1 = wp[4], bf2 = wp[8], bf3 = wp[12];
        const float pre = fmaf(t, v1g[n], b1g[n]);
        const float sk  = sg[n];
        v4f acc = {0.f, 0.f, 0.f, 0.f};
        acc = __builtin_amdgcn_mfma_f32_16x16x32_bf16(af[0], bf0, acc, 0, 0, 0);
        acc = __builtin_amdgcn_mfma_f32_16x16x32_bf16(af[1], bf1, acc, 0, 0, 0);
        acc = __builtin_amdgcn_mfma_f32_16x16x32_bf16(af[2], bf2, acc, 0, 0, 0);
        acc = __builtin_amdgcn_mfma_f32_16x16x32_bf16(af[3], bf3, acc, 0, 0, 0);

#pragma unroll
        for (int reg = 0; reg < 4; ++reg) {
            float x  = acc[reg] + pre;
            // tanh(x) = 1 - 2/(e^{2x}+1); saturates cleanly
            float e  = __expf(2.f * x);
            float th = 1.f - 2.f * __builtin_amdgcn_rcpf(e + 1.f);
            hsm[(quad * 4 + reg) * 520 + n] = f2bf(th);
            dacc[reg] = fmaf(1.f - th * th, sk, dacc[reg]);
        }
    }

    // divergence: reduce across the 16 m-lanes of each quad (rows preserved)
#pragma unroll
    for (int reg = 0; reg < 4; ++reg) {
        float v = dacc[reg];
        v += __shfl_xor(v, 1, 64);
        v += __shfl_xor(v, 2, 64);
        v += __shfl_xor(v, 4, 64);
        v += __shfl_xor(v, 8, 64);
        dacc[reg] = v;
    }
    if (m == 0) {
#pragma unroll
        for (int reg = 0; reg < 4; ++reg) divp[wv][quad * 4 + reg] = dacc[reg];
    }

    // ---- GEMM2 setup: prefetch W2 fragments BEFORE the barrier ----
    const int d = wv * 16 + m;                    // this wave's output column
    const v8s* w2p_ = (const v8s*)&W2T[d * H_ + quad * 8];
    const float be = b2g[d];
    v8s w2p[8];
#pragma unroll
    for (int kki = 0; kki < 8; ++kki) w2p[kki] = w2p_[kki * 4];

    __syncthreads();   // h tile + div partials ready

    if (tid < 16) {
        float dv = 0.f;
#pragma unroll
        for (int w = 0; w < 8; ++w) dv += divp[w][tid];
        out[B_ * D_ + row0 + tid] = -dv;
    }

    // ---- GEMM2: dy = h @ W2 + b2 ----
    v4f acc2 = {0.f, 0.f, 0.f, 0.f};
    const v8s* hrow = (const v8s*)&hsm[m * 520 + quad * 8];   // k step: +4 v8s
#pragma unroll
    for (int kki = 0; kki < 8; ++kki) {
        v8s a = hrow[kki * 4];
        acc2 = __builtin_amdgcn_mfma_f32_16x16x32_bf16(a, w2p[kki], acc2, 0, 0, 0);
    }
#pragma unroll
    for (int kki = 8; kki < 16; ++kki) {
        v8s a = hrow[kki * 4];
        v8s b = w2p_[kki * 4];
        acc2 = __builtin_amdgcn_mfma_f32_16x16x32_bf16(a, b, acc2, 0, 0, 0);
    }
#pragma unroll
    for (int reg = 0; reg < 4; ++reg) {
        const int r = row0 + quad * 4 + reg;
        out[r * D_ + d] = acc2[reg] + be;
    }
}

extern "C" void kernel_launch(void* const* d_in, const int* in_sizes, int n_in,
                              void* d_out, int out_size, void* d_ws, size_t ws_size,
                              hipStream_t stream) {
    const float* t  = (const float*)d_in[0];
    const float* y  = (const float*)d_in[1];
    // d_in[2] = logp (unused)
    const float* W1 = (const float*)d_in[3];
    const float* b1 = (const float*)d_in[4];
    const float* v1 = (const float*)d_in[5];
    const float* W2 = (const float*)d_in[6];
    const float* b2 = (const float*)d_in[7];
    float* out = (float*)d_out;

    char* ws = (char*)d_ws;
    unsigned short* W1T = (unsigned short*)(ws);             // 131,072 B
    unsigned short* W2T = (unsigned short*)(ws + 131072);    // 131,072 B
    float*          s   = (float*)(ws + 262144);             //   2,048 B

    prep_kernel<<<136, 256, 0, stream>>>(W1, W2, W1T, W2T, s);
    ode_mfma<<<B_ / 16, 512, 0, stream>>>(t, y, W1T, W2T, s, b1, v1, b2, out);
}